// Round 15
// baseline (4431.537 us; speedup 1.0000x reference)
//
#include <hip/hip_runtime.h>
#include <stdint.h>
#include <cstdio>

typedef unsigned short u16;
typedef __attribute__((ext_vector_type(8))) __bf16 bf16x8;
typedef __attribute__((ext_vector_type(4))) float f32x4;
typedef __attribute__((ext_vector_type(4))) int i32x4;

#define AGENT __HIP_MEMORY_SCOPE_AGENT

__device__ __forceinline__ float bf2f(u16 u) {
  unsigned int x = ((unsigned int)u) << 16;
  return __builtin_bit_cast(float, x);
}
__device__ __forceinline__ u16 f2bf(float f) {
  unsigned int x = __builtin_bit_cast(unsigned int, f);
  unsigned int r = (x + 0x7fffu + ((x >> 16) & 1u)) >> 16;
  return (u16)r;
}
__device__ __forceinline__ float sigm(float x) { return 1.f / (1.f + __expf(-x)); }
__device__ __forceinline__ float tanh_f(float x) { return 1.f - 2.f / (__expf(2.f * x) + 1.f); }

// ---------- fp32 -> bf16 convert (x) ----------
__global__ __launch_bounds__(256) void k_cvt(const float* __restrict__ in, u16* __restrict__ out, int n4) {
  int i = blockIdx.x * 256 + threadIdx.x;
  if (i >= n4) return;
  float4 f = ((const float4*)in)[i];
  ushort4 o;
  o.x = f2bf(f.x); o.y = f2bf(f.y); o.z = f2bf(f.z); o.w = f2bf(f.w);
  ((ushort4*)out)[i] = o;
}

// ---------- pack Wx0 [768][3072] -> B-fragment order [nt=192][kt=24][lane=64][j=8] ----------
__global__ __launch_bounds__(256) void k_pack_wx(const float* __restrict__ Wx, u16* __restrict__ Bp) {
  int idx = blockIdx.x * 256 + threadIdx.x;
  if (idx >= 2359296) return;
  int j = idx & 7;
  int l = (idx >> 3) & 63;
  int t = idx >> 9;          // nt*24 + kt
  int kt = t % 24, nt = t / 24;
  int k = kt * 32 + (l >> 4) * 8 + j;
  int n = nt * 16 + (l & 15);
  Bp[idx] = f2bf(Wx[(size_t)k * 3072 + n]);
}

// ---------- pack W[768][3072] -> per-member A-operand slices [w=32][nt=6][kt=24][lane=64][j=8] ----------
// col order within 16-col tile: cc = 4*vi + q (vi = unit-in-wave 0..3, q = gate 0..3)
// Used for Wh0, Wh1, and Wx1 (all are [768][3072] with flax gate order).
__global__ __launch_bounds__(256) void k_pack_wh(const float* __restrict__ Wh, u16* __restrict__ Wp) {
  int idx = blockIdx.x * 256 + threadIdx.x;
  if (idx >= 2359296) return;
  int j = idx & 7;
  int l = (idx >> 3) & 63;
  int t = idx >> 9;          // w*144 + nt*24 + kt
  int kt = t % 24;
  int tmp = t / 24;          // w*6 + nt
  int nt = tmp % 6, w = tmp / 6;
  int k = kt * 32 + (l >> 4) * 8 + j;
  int cc = l & 15;
  int vi = cc >> 2, q = cc & 3;
  int gcol = q * 768 + w * 24 + nt * 4 + vi;
  Wp[idx] = f2bf(Wh[(size_t)k * 3072 + gcol]);
}

// ---------- GEMM: xg[16384][3072] bf16 = x_bf[16384][768] @ Wxp0 ----------
__global__ __launch_bounds__(256, 2) void k_gemm(const u16* __restrict__ A, const u16* __restrict__ Bp,
                                                 u16* __restrict__ C) {
  const int bid = blockIdx.x;
  const int bm = bid & 127, bn = bid >> 7;   // 128 x 24
  const int tid = threadIdx.x, lane = tid & 63, wv = tid >> 6;
  const int wm = wv >> 1, wn = wv & 1;
  const int row0 = bm * 128 + wm * 64;
  const int col0 = bn * 128 + wn * 64;
  const int rlo = lane & 15, rhi = lane >> 4;
  f32x4 acc[4][4] = {};
  const u16* Ab = A + (size_t)(row0 + rlo) * 768 + rhi * 8;
  const u16* Bb = Bp + ((size_t)(bn * 8 + wn * 4) * 24 * 64 + lane) * 8;
#pragma unroll 2
  for (int kt = 0; kt < 24; ++kt) {
    bf16x8 a[4], b[4];
#pragma unroll
    for (int i = 0; i < 4; ++i) a[i] = *(const bf16x8*)(Ab + (size_t)i * 16 * 768 + kt * 32);
#pragma unroll
    for (int j = 0; j < 4; ++j) b[j] = *(const bf16x8*)(Bb + (size_t)j * 24 * 64 * 8 + (size_t)kt * 64 * 8);
#pragma unroll
    for (int i = 0; i < 4; ++i)
#pragma unroll
      for (int j = 0; j < 4; ++j)
        acc[i][j] = __builtin_amdgcn_mfma_f32_16x16x32_bf16(a[i], b[j], acc[i][j], 0, 0, 0);
  }
#pragma unroll
  for (int i = 0; i < 4; ++i)
#pragma unroll
    for (int j = 0; j < 4; ++j)
#pragma unroll
      for (int r = 0; r < 4; ++r) {
        int row = row0 + i * 16 + rhi * 4 + r;
        int col = col0 + j * 16 + rlo;
        C[(size_t)row * 3072 + col] = f2bf(acc[i][j][r]);
      }
}

// ---------- fused 2-layer persistent LSTM recurrence (1-step software pipeline) ----------
// 256 WGs x 384 threads (6 waves), 1 WG/CU (LDS-forced). Groups: g = wid&7 (4 seqs),
// member w = wid>>3 (24 units). Wave wv owns one 16-col tile = 4 gates x 4 units.
// Weights: Wh0 + Wh1 frags in registers (AGPR-resident), Wx1 slice (147 KB) in LDS.
// Macro-step t (0..512): poll h0_{t-1} (tag t, slot t&1) and h1_{t-2} (tag t-1, slot (t-1)&1)
//   -> B_A -> stage h0lds/h1lds -> B3
//   -> [t<512]  L0: gates0 = Wh0 x h0_{t-1}; cell -> h0_t; publish (tag t+1, slot (t+1)&1)
//   -> sched_barrier(0)  (keeps the critical L0 publish early)
//   -> [t>=1]   L1: gates1 = Wx1(LDS) x h0_{t-1} + Wh1 x h1_{t-2}; cell -> h1_{t-1};
//               publish (tag t, slot t&1); store out row t-1.
// 2-slot overwrite safety: publisher's poll-gate at step s requires ALL members' step s-1
// publishes, each of which is program-ordered AFTER that member's step s-1 capture (both bufs).
__global__ __launch_bounds__(384) void k_rec2(
    const u16* __restrict__ xg,     // [16384][3072] bf16 (layer-0 input proj)
    const u16* __restrict__ Whp0,   // [32][6][24][64][8]
    const u16* __restrict__ Whp1,   // [32][6][24][64][8]
    const u16* __restrict__ Wxp1,   // [32][6][24][64][8] (Wx1 packed like Wh)
    const float* __restrict__ b0,
    const float* __restrict__ b1,
    int* hbuf0,                     // [8][2][3072] tagged dwords (zeroed)
    int* hbuf1,                     // [8][2][3072] tagged dwords (zeroed)
    float* __restrict__ out) {      // [32][512][768] fp32 (pre-LN)
  __shared__ __align__(16) u16 wxlds[73728];   // 147456 B: this member's Wx1 slice
  __shared__ __align__(16) int h0lds[1600];    // h0_{t-1}[4 seq][768], rows padded to 400 dw
  __shared__ __align__(16) int h1lds[1600];    // h1_{t-2}[4 seq][768]

  const int wid = blockIdx.x, g = wid & 7, w = wid >> 3;
  const int tid = threadIdx.x, lane = tid & 63, wv = tid >> 6;

  // ---- Wx1 slice -> LDS (layout identical to packed global; contiguous copy) ----
  {
    const int4* s4 = (const int4*)(Wxp1 + (size_t)w * 73728);
    int4* d4 = (int4*)wxlds;
    for (int i = tid; i < 9216; i += 384) d4[i] = s4[i];
  }

  // ---- Wh0 + Wh1 fragments -> registers (compiler parks in AGPRs; R12/R14-verified) ----
  bf16x8 w0E[12], w0O[12], w1E[12], w1O[12];
  {
    const u16* bp0 = Whp0 + (((size_t)(w * 6 + wv) * 24) * 64 + lane) * 8;
    const u16* bp1 = Whp1 + (((size_t)(w * 6 + wv) * 24) * 64 + lane) * 8;
#pragma unroll
    for (int kk = 0; kk < 12; ++kk) {
      w0E[kk] = *(const bf16x8*)(bp0 + (size_t)(2 * kk) * 512);
      w0O[kk] = *(const bf16x8*)(bp0 + (size_t)(2 * kk + 1) * 512);
      w1E[kk] = *(const bf16x8*)(bp1 + (size_t)(2 * kk) * 512);
      w1O[kk] = *(const bf16x8*)(bp1 + (size_t)(2 * kk + 1) * 512);
    }
  }

  // ---- cell role: lane = 16*vi + r owns cell (seq r, unit vi) ----
  const bool cellt = (lane & 15) < 4;
  const int vi = lane >> 4, r = lane & 3;
  const int unit = w * 24 + wv * 4 + vi;
  const int seq = g * 4 + r;
  float bA0 = 0, bA1 = 0, bA2 = 0, bA3 = 0;   // layer-0 biases
  float bB0 = 0, bB1 = 0, bB2 = 0, bB3 = 0;   // layer-1 biases
  float xv0 = 0, xv1 = 0, xv2 = 0, xv3 = 0;   // layer-0 xg prefetch
  if (cellt) {
    bA0 = b0[unit]; bA1 = b0[768 + unit]; bA2 = b0[1536 + unit]; bA3 = b0[2304 + unit];
    bB0 = b1[unit]; bB1 = b1[768 + unit]; bB2 = b1[1536 + unit]; bB3 = b1[2304 + unit];
    const u16* xr = xg + (size_t)seq * 512 * 3072;
    xv0 = bf2f(xr[unit]); xv1 = bf2f(xr[768 + unit]);
    xv2 = bf2f(xr[1536 + unit]); xv3 = bf2f(xr[2304 + unit]);
  }
  float cst0 = 0.f, cst1 = 0.f;
  const int sl = (lane & 15) < 4 ? (lane & 15) : 3;      // h-frag row (pad rows clamped)
  const int abase = sl * 400 + (lane >> 4) * 4;          // h-frag dword base
  const int c = tid;                                     // poll chunk id (8 dwords per buffer)
  const int hrow = c / 96, hcol = (c % 96) * 4;          // staged int4 slot
  const u16* wx_base = wxlds + ((size_t)wv * 24 * 64 + lane) * 8;  // Wx1 frag base (u16)
  int guard = 0;

  __syncthreads();  // wxlds staged

  for (int t = 0; t <= 512; ++t) {
    // ---- merged poll+fetch: h0 (tag t) and, for t>=1, h1 (tag t-1) in one loop ----
    const int e0 = t, e1 = t - 1;
    int* s0 = hbuf0 + (size_t)(g * 2 + (t & 1)) * 3072;
    int* s1 = hbuf1 + (size_t)(g * 2 + ((t - 1) & 1)) * 3072;
    const int* p00 = s0 + 8 * c;
    const int* p01 = p00 + 4;
    const int* p10 = s1 + 8 * c;
    const int* p11 = p10 + 4;
    i32x4 va, vb, vc, vd;
    if (t >= 1) {
      for (;;) {
        asm volatile("global_load_dwordx4 %0, %4, off sc0 sc1\n\t"
                     "global_load_dwordx4 %1, %5, off sc0 sc1\n\t"
                     "global_load_dwordx4 %2, %6, off sc0 sc1\n\t"
                     "global_load_dwordx4 %3, %7, off sc0 sc1\n\t"
                     "s_waitcnt vmcnt(0)"
                     : "=&v"(va), "=&v"(vb), "=&v"(vc), "=&v"(vd)
                     : "v"(p00), "v"(p01), "v"(p10), "v"(p11)
                     : "memory");
        bool ok = true;
#pragma unroll
        for (int j = 0; j < 4; ++j)
          ok = ok && ((va[j] & 0xffff) == e0) && ((vb[j] & 0xffff) == e0) &&
               ((vc[j] & 0xffff) == e1) && ((vd[j] & 0xffff) == e1);
        if (ok || ++guard > (1 << 22)) break;
      }
    } else {
      for (;;) {
        asm volatile("global_load_dwordx4 %0, %2, off sc0 sc1\n\t"
                     "global_load_dwordx4 %1, %3, off sc0 sc1\n\t"
                     "s_waitcnt vmcnt(0)"
                     : "=&v"(va), "=&v"(vb)
                     : "v"(p00), "v"(p01)
                     : "memory");
        bool ok = true;
#pragma unroll
        for (int j = 0; j < 4; ++j)
          ok = ok && ((va[j] & 0xffff) == e0) && ((vb[j] & 0xffff) == e0);
        if (ok || ++guard > (1 << 22)) break;
      }
    }
    __syncthreads();  // B_A: all waves done reading h0lds/h1lds (step t-1 MFMAs)

    {
      int4 pk;
      pk.x = (int)(((unsigned)va[0] >> 16) | ((unsigned)va[1] & 0xffff0000u));
      pk.y = (int)(((unsigned)va[2] >> 16) | ((unsigned)va[3] & 0xffff0000u));
      pk.z = (int)(((unsigned)vb[0] >> 16) | ((unsigned)vb[1] & 0xffff0000u));
      pk.w = (int)(((unsigned)vb[2] >> 16) | ((unsigned)vb[3] & 0xffff0000u));
      *(int4*)&h0lds[hrow * 400 + hcol] = pk;
      if (t >= 1) {
        pk.x = (int)(((unsigned)vc[0] >> 16) | ((unsigned)vc[1] & 0xffff0000u));
        pk.y = (int)(((unsigned)vc[2] >> 16) | ((unsigned)vc[3] & 0xffff0000u));
        pk.z = (int)(((unsigned)vd[0] >> 16) | ((unsigned)vd[1] & 0xffff0000u));
        pk.w = (int)(((unsigned)vd[2] >> 16) | ((unsigned)vd[3] & 0xffff0000u));
        *(int4*)&h1lds[hrow * 400 + hcol] = pk;
      }
    }
    __syncthreads();  // B3: h staged

    // ================= layer 0 (t < 512): the critical chain =================
    if (t < 512) {
      f32x4 a0 = {0, 0, 0, 0}, a1 = {0, 0, 0, 0};
#pragma unroll
      for (int kk = 0; kk < 12; ++kk) {
        bf16x8 he = *(const bf16x8*)(h0lds + abase + (2 * kk) * 16);
        bf16x8 ho = *(const bf16x8*)(h0lds + abase + (2 * kk + 1) * 16);
        a0 = __builtin_amdgcn_mfma_f32_16x16x32_bf16(w0E[kk], he, a0, 0, 0, 0);
        a1 = __builtin_amdgcn_mfma_f32_16x16x32_bf16(w0O[kk], ho, a1, 0, 0, 0);
      }
      a0 += a1;
      if (cellt) {
        float p0g = xv0 + a0[0] + bA0;
        float p1g = xv1 + a0[1] + bA1;
        float p2g = xv2 + a0[2] + bA2;
        float p3g = xv3 + a0[3] + bA3;
        float ig = sigm(p0g), fg = sigm(p1g), gg = tanh_f(p2g), og = sigm(p3g);
        cst0 = fg * cst0 + ig * gg;
        float h = og * tanh_f(cst0);
        int* dst = hbuf0 + (size_t)(g * 2 + ((t + 1) & 1)) * 3072 + r * 768 + unit;
        int val = (int)(((unsigned)f2bf(h) << 16) | (unsigned)(t + 1));
        __hip_atomic_store(dst, val, __ATOMIC_RELAXED, AGENT);  // gates the group's next step
        if (t + 1 < 512) {
          const u16* xr = xg + ((size_t)seq * 512 + t + 1) * 3072;
          xv0 = bf2f(xr[unit]); xv1 = bf2f(xr[768 + unit]);
          xv2 = bf2f(xr[1536 + unit]); xv3 = bf2f(xr[2304 + unit]);
        }
      }
    }
    __builtin_amdgcn_sched_barrier(0);  // keep L0 publish ahead of L1 work

    // ================= layer 1 (t >= 1): runs in the handshake shadow =================
    if (t >= 1) {
      f32x4 c0 = {0, 0, 0, 0}, c1 = {0, 0, 0, 0};
#pragma unroll
      for (int kk = 0; kk < 12; ++kk) {   // xg1 part: Wx1(LDS) x h0_{t-1}
        bf16x8 xe = *(const bf16x8*)(wx_base + (size_t)(2 * kk) * 512);
        bf16x8 xo = *(const bf16x8*)(wx_base + (size_t)(2 * kk + 1) * 512);
        bf16x8 he = *(const bf16x8*)(h0lds + abase + (2 * kk) * 16);
        bf16x8 ho = *(const bf16x8*)(h0lds + abase + (2 * kk + 1) * 16);
        c0 = __builtin_amdgcn_mfma_f32_16x16x32_bf16(xe, he, c0, 0, 0, 0);
        c1 = __builtin_amdgcn_mfma_f32_16x16x32_bf16(xo, ho, c1, 0, 0, 0);
      }
#pragma unroll
      for (int kk = 0; kk < 12; ++kk) {   // recurrent part: Wh1 x h1_{t-2}
        bf16x8 he = *(const bf16x8*)(h1lds + abase + (2 * kk) * 16);
        bf16x8 ho = *(const bf16x8*)(h1lds + abase + (2 * kk + 1) * 16);
        c0 = __builtin_amdgcn_mfma_f32_16x16x32_bf16(w1E[kk], he, c0, 0, 0, 0);
        c1 = __builtin_amdgcn_mfma_f32_16x16x32_bf16(w1O[kk], ho, c1, 0, 0, 0);
      }
      c0 += c1;
      if (cellt) {
        float p0g = c0[0] + bB0;
        float p1g = c0[1] + bB1;
        float p2g = c0[2] + bB2;
        float p3g = c0[3] + bB3;
        float ig = sigm(p0g), fg = sigm(p1g), gg = tanh_f(p2g), og = sigm(p3g);
        cst1 = fg * cst1 + ig * gg;
        float h = og * tanh_f(cst1);
        int* dst = hbuf1 + (size_t)(g * 2 + (t & 1)) * 3072 + r * 768 + unit;
        int val = (int)(((unsigned)f2bf(h) << 16) | (unsigned)t);
        __hip_atomic_store(dst, val, __ATOMIC_RELAXED, AGENT);
        out[((size_t)seq * 512 + (t - 1)) * 768 + unit] = h;
      }
    }
  }
}

// ---------- LayerNorm (in-place safe) ----------
__global__ __launch_bounds__(256) void k_ln(const float* __restrict__ in, const float* __restrict__ sc,
                                            const float* __restrict__ bi, float* __restrict__ out) {
  const int row = blockIdx.x, tid = threadIdx.x;
  const float* x = in + (size_t)row * 768;
  float v0 = x[tid], v1 = x[tid + 256], v2 = x[tid + 512];
  float s = v0 + v1 + v2;
  float s2 = v0 * v0 + v1 * v1 + v2 * v2;
#pragma unroll
  for (int off = 32; off >= 1; off >>= 1) {
    s += __shfl_xor(s, off);
    s2 += __shfl_xor(s2, off);
  }
  __shared__ float red[8];
  const int wv = tid >> 6;
  if ((tid & 63) == 0) { red[wv] = s; red[4 + wv] = s2; }
  __syncthreads();
  s = red[0] + red[1] + red[2] + red[3];
  s2 = red[4] + red[5] + red[6] + red[7];
  float mean = s * (1.f / 768.f);
  float var = s2 * (1.f / 768.f) - mean * mean;
  float rs = rsqrtf(var + 1e-6f);
  float* o = out + (size_t)row * 768;
  o[tid] = (v0 - mean) * rs * sc[tid] + bi[tid];
  o[tid + 256] = (v1 - mean) * rs * sc[tid + 256] + bi[tid + 256];
  o[tid + 512] = (v2 - mean) * rs * sc[tid + 512] + bi[tid + 512];
}

extern "C" void kernel_launch(void* const* d_in, const int* in_sizes, int n_in,
                              void* d_out, int out_size, void* d_ws, size_t ws_size,
                              hipStream_t stream) {
  const float* x   = (const float*)d_in[0];
  const float* Wx0 = (const float*)d_in[1];
  const float* Wh0 = (const float*)d_in[2];
  const float* b0  = (const float*)d_in[3];
  const float* Wx1 = (const float*)d_in[4];
  const float* Wh1 = (const float*)d_in[5];
  const float* b1  = (const float*)d_in[6];
  const float* lns = (const float*)d_in[7];
  const float* lnb = (const float*)d_in[8];
  float* out = (float*)d_out;

  char* p = (char*)d_ws;
  auto alloc = [&](size_t bytes) {
    char* r = p;
    p += (bytes + 255) & ~(size_t)255;
    return r;
  };
  u16* xg    = (u16*)alloc(16384ull * 3072 * 2);
  u16* xbf   = (u16*)alloc(16384ull * 768 * 2);
  u16* Wxp0  = (u16*)alloc(2359296ull * 2);
  u16* Whp0s = (u16*)alloc(2359296ull * 2);
  u16* Whp1s = (u16*)alloc(2359296ull * 2);
  u16* Wxp1s = (u16*)alloc(2359296ull * 2);
  char* sync0 = alloc(196608ull * 2);   // hbuf0, hbuf1 (tagged dwords)
  int* hbuf0 = (int*)sync0;
  int* hbuf1 = (int*)(sync0 + 196608);

  if ((size_t)(p - (char*)d_ws) > ws_size) {
    fprintf(stderr, "kernel_launch: ws too small: need %zu have %zu\n",
            (size_t)(p - (char*)d_ws), ws_size);
    return;
  }

  hipMemsetAsync(sync0, 0, 196608ull * 2, stream);
  k_cvt<<<12288, 256, 0, stream>>>(x, xbf, 3145728);
  k_pack_wx<<<9216, 256, 0, stream>>>(Wx0, Wxp0);
  k_pack_wh<<<9216, 256, 0, stream>>>(Wh0, Whp0s);
  k_pack_wh<<<9216, 256, 0, stream>>>(Wh1, Whp1s);
  k_pack_wh<<<9216, 256, 0, stream>>>(Wx1, Wxp1s);

  k_gemm<<<3072, 256, 0, stream>>>(xbf, Wxp0, xg);
  k_rec2<<<256, 384, 0, stream>>>(xg, Whp0s, Whp1s, Wxp1s, b0, b1, hbuf0, hbuf1, (float*)d_out);
  k_ln<<<16384, 256, 0, stream>>>((const float*)d_out, lns, lnb, out);
}

// Round 16
// 4034.364 us; speedup vs baseline: 1.0984x; 1.0984x over previous
//
#include <hip/hip_runtime.h>
#include <stdint.h>
#include <cstdio>

typedef unsigned short u16;
typedef __attribute__((ext_vector_type(8))) __bf16 bf16x8;
typedef __attribute__((ext_vector_type(4))) float f32x4;
typedef __attribute__((ext_vector_type(4))) int i32x4;

#define AGENT __HIP_MEMORY_SCOPE_AGENT

__device__ __forceinline__ float bf2f(u16 u) {
  unsigned int x = ((unsigned int)u) << 16;
  return __builtin_bit_cast(float, x);
}
__device__ __forceinline__ u16 f2bf(float f) {
  unsigned int x = __builtin_bit_cast(unsigned int, f);
  unsigned int r = (x + 0x7fffu + ((x >> 16) & 1u)) >> 16;
  return (u16)r;
}
__device__ __forceinline__ float sigm(float x) { return 1.f / (1.f + __expf(-x)); }
__device__ __forceinline__ float tanh_f(float x) { return 1.f - 2.f / (__expf(2.f * x) + 1.f); }
__device__ __forceinline__ int pk2(int lo, int hi) {
  return (int)(((unsigned)lo >> 16) | ((unsigned)hi & 0xffff0000u));
}

// ---------- fp32 -> bf16 convert (x) ----------
__global__ __launch_bounds__(256) void k_cvt(const float* __restrict__ in, u16* __restrict__ out, int n4) {
  int i = blockIdx.x * 256 + threadIdx.x;
  if (i >= n4) return;
  float4 f = ((const float4*)in)[i];
  ushort4 o;
  o.x = f2bf(f.x); o.y = f2bf(f.y); o.z = f2bf(f.z); o.w = f2bf(f.w);
  ((ushort4*)out)[i] = o;
}

// ---------- pack Wx0 [768][3072] -> B-fragment order [nt=192][kt=24][lane=64][j=8] ----------
__global__ __launch_bounds__(256) void k_pack_wx(const float* __restrict__ Wx, u16* __restrict__ Bp) {
  int idx = blockIdx.x * 256 + threadIdx.x;
  if (idx >= 2359296) return;
  int j = idx & 7;
  int l = (idx >> 3) & 63;
  int t = idx >> 9;          // nt*24 + kt
  int kt = t % 24, nt = t / 24;
  int k = kt * 32 + (l >> 4) * 8 + j;
  int n = nt * 16 + (l & 15);
  Bp[idx] = f2bf(Wx[(size_t)k * 3072 + n]);
}

// ---------- pack W[768][3072] -> per-member A-operand slices [w=32][nt=6][kt=24][lane=64][j=8] ----------
// col order within 16-col tile: cc = 4*vi + q (vi = unit-in-wave 0..3, q = gate 0..3)
// Used for Wh0, Wh1, and Wx1.
__global__ __launch_bounds__(256) void k_pack_wh(const float* __restrict__ Wh, u16* __restrict__ Wp) {
  int idx = blockIdx.x * 256 + threadIdx.x;
  if (idx >= 2359296) return;
  int j = idx & 7;
  int l = (idx >> 3) & 63;
  int t = idx >> 9;          // w*144 + nt*24 + kt
  int kt = t % 24;
  int tmp = t / 24;          // w*6 + nt
  int nt = tmp % 6, w = tmp / 6;
  int k = kt * 32 + (l >> 4) * 8 + j;
  int cc = l & 15;
  int vi = cc >> 2, q = cc & 3;
  int gcol = q * 768 + w * 24 + nt * 4 + vi;
  Wp[idx] = f2bf(Wh[(size_t)k * 3072 + gcol]);
}

// ---------- GEMM: xg[16384][3072] bf16 = x_bf[16384][768] @ Wxp0 ----------
__global__ __launch_bounds__(256, 2) void k_gemm(const u16* __restrict__ A, const u16* __restrict__ Bp,
                                                 u16* __restrict__ C) {
  const int bid = blockIdx.x;
  const int bm = bid & 127, bn = bid >> 7;   // 128 x 24
  const int tid = threadIdx.x, lane = tid & 63, wv = tid >> 6;
  const int wm = wv >> 1, wn = wv & 1;
  const int row0 = bm * 128 + wm * 64;
  const int col0 = bn * 128 + wn * 64;
  const int rlo = lane & 15, rhi = lane >> 4;
  f32x4 acc[4][4] = {};
  const u16* Ab = A + (size_t)(row0 + rlo) * 768 + rhi * 8;
  const u16* Bb = Bp + ((size_t)(bn * 8 + wn * 4) * 24 * 64 + lane) * 8;
#pragma unroll 2
  for (int kt = 0; kt < 24; ++kt) {
    bf16x8 a[4], b[4];
#pragma unroll
    for (int i = 0; i < 4; ++i) a[i] = *(const bf16x8*)(Ab + (size_t)i * 16 * 768 + kt * 32);
#pragma unroll
    for (int j = 0; j < 4; ++j) b[j] = *(const bf16x8*)(Bb + (size_t)j * 24 * 64 * 8 + (size_t)kt * 64 * 8);
#pragma unroll
    for (int i = 0; i < 4; ++i)
#pragma unroll
      for (int j = 0; j < 4; ++j)
        acc[i][j] = __builtin_amdgcn_mfma_f32_16x16x32_bf16(a[i], b[j], acc[i][j], 0, 0, 0);
  }
#pragma unroll
  for (int i = 0; i < 4; ++i)
#pragma unroll
    for (int j = 0; j < 4; ++j)
#pragma unroll
      for (int r = 0; r < 4; ++r) {
        int row = row0 + i * 16 + rhi * 4 + r;
        int col = col0 + j * 16 + rlo;
        C[(size_t)row * 3072 + col] = f2bf(acc[i][j][r]);
      }
}

// ---------- fused 2-layer persistent LSTM recurrence (1-step pipeline, budget-solved) ----------
// 256 WGs x 256 threads (4 waves -> 1 wave/SIMD -> 512-reg budget, no spill).
// Groups: g = wid&7 (4 seqs), member w = wid>>3 (24 units = 6 col-tiles of 16).
// Tile ownership (72 frags = 288 regs per wave):
//   waves 0,1 (path A): L0 tiles {2wv, 2wv+1} (Wh0) + L1 tile {4+wv} (Wh1)
//   waves 2,3 (path B): L0 tile {2+wv} (Wh0)      + L1 tiles {2(wv-2), +1} (Wh1)
// Wx1 slice (147 KB) in LDS; L1 gates = Wx1(LDS) x h0_{t-1} + Wh1(reg) x h1_{t-2}.
// Macro-step t (0..512): poll h0_{t-1} (tag t) then poll h1_{t-2} (tag t-1) in SEPARATE
// loops (only the late buffer re-fetched while spinning) -> B_A -> stage -> B3 ->
// L0 (t<512): MFMA+cell+publish h0_t (tag t+1)  -> sched_barrier ->
// L1 (t>=1): MFMA+cell+publish h1_{t-1} (tag t) + out row t-1.
// 2-slot overwrite safety: both polls gate every publish (see R15 induction argument).
__global__ __launch_bounds__(256, 1) void k_rec2(
    const u16* __restrict__ xg,     // [16384][3072] bf16
    const u16* __restrict__ Whp0,   // [32][6][24][64][8]
    const u16* __restrict__ Whp1,   // [32][6][24][64][8]
    const u16* __restrict__ Wxp1,   // [32][6][24][64][8]
    const float* __restrict__ b0,
    const float* __restrict__ b1,
    int* hbuf0,                     // [8][2][3072] tagged dwords (zeroed)
    int* hbuf1,                     // [8][2][3072] tagged dwords (zeroed)
    float* __restrict__ out) {      // [32][512][768] fp32 (pre-LN)
  __shared__ __align__(16) u16 wxlds[73728];   // 147456 B Wx1 slice
  __shared__ __align__(16) int h0lds[1600];    // h0_{t-1}[4][768], rows padded to 400 dw
  __shared__ __align__(16) int h1lds[1600];    // h1_{t-2}[4][768]

  const int wid = blockIdx.x, g = wid & 7, w = wid >> 3;
  const int tid = threadIdx.x, lane = tid & 63, wv = tid >> 6;   // wv 0..3

  { // Wx1 slice -> LDS
    const int4* s4 = (const int4*)(Wxp1 + (size_t)w * 73728);
    int4* d4 = (int4*)wxlds;
    for (int i = tid; i < 9216; i += 256) d4[i] = s4[i];
  }

  const bool pA = (wv < 2);
  const int tA = pA ? (2 * wv) : (2 + wv);        // L0 tile (all waves)
  const int tB = pA ? (2 * wv + 1) : 0;           // 2nd L0 tile (path A)
  const int tC = pA ? (4 + wv) : (2 * (wv - 2));  // 1st L1 tile (all waves)
  const int tD = pA ? 0 : (2 * (wv - 2) + 1);     // 2nd L1 tile (path B)

  // ---- weight frags -> registers: fA=Wh0[tA]; fB = pA?Wh0[tB]:Wh1[tC]; fC = pA?Wh1[tC]:Wh1[tD]
  bf16x8 fA[24], fB[24], fC[24];
  {
    const u16* ap = Whp0 + ((size_t)(w * 6 + tA) * 24 * 64 + lane) * 8;
    const u16* bp = pA ? (Whp0 + ((size_t)(w * 6 + tB) * 24 * 64 + lane) * 8)
                       : (Whp1 + ((size_t)(w * 6 + tC) * 24 * 64 + lane) * 8);
    const u16* cp = pA ? (Whp1 + ((size_t)(w * 6 + tC) * 24 * 64 + lane) * 8)
                       : (Whp1 + ((size_t)(w * 6 + tD) * 24 * 64 + lane) * 8);
#pragma unroll
    for (int kt = 0; kt < 24; ++kt) {
      fA[kt] = *(const bf16x8*)(ap + (size_t)kt * 512);
      fB[kt] = *(const bf16x8*)(bp + (size_t)kt * 512);
      fC[kt] = *(const bf16x8*)(cp + (size_t)kt * 512);
    }
  }

  // ---- cell roles: lane = 16*vi + r ----
  const bool cellt = (lane & 15) < 4;
  const int vi = lane >> 4, r = lane & 3;
  const int seq = g * 4 + r;
  const int uA = w * 24 + tA * 4 + vi;
  const int uB = w * 24 + tB * 4 + vi;
  const int uC = w * 24 + tC * 4 + vi;
  const int uD = w * 24 + tD * 4 + vi;
  float bA0 = 0, bA1 = 0, bA2 = 0, bA3 = 0, bB0 = 0, bB1 = 0, bB2 = 0, bB3 = 0;
  float bC0 = 0, bC1 = 0, bC2 = 0, bC3 = 0, bD0 = 0, bD1 = 0, bD2 = 0, bD3 = 0;
  float xA0 = 0, xA1 = 0, xA2 = 0, xA3 = 0, xB0 = 0, xB1 = 0, xB2 = 0, xB3 = 0;
  if (cellt) {
    bA0 = b0[uA]; bA1 = b0[768 + uA]; bA2 = b0[1536 + uA]; bA3 = b0[2304 + uA];
    bC0 = b1[uC]; bC1 = b1[768 + uC]; bC2 = b1[1536 + uC]; bC3 = b1[2304 + uC];
    const u16* xr = xg + (size_t)seq * 512 * 3072;
    xA0 = bf2f(xr[uA]); xA1 = bf2f(xr[768 + uA]);
    xA2 = bf2f(xr[1536 + uA]); xA3 = bf2f(xr[2304 + uA]);
    if (pA) {
      bB0 = b0[uB]; bB1 = b0[768 + uB]; bB2 = b0[1536 + uB]; bB3 = b0[2304 + uB];
      xB0 = bf2f(xr[uB]); xB1 = bf2f(xr[768 + uB]);
      xB2 = bf2f(xr[1536 + uB]); xB3 = bf2f(xr[2304 + uB]);
    } else {
      bD0 = b1[uD]; bD1 = b1[768 + uD]; bD2 = b1[1536 + uD]; bD3 = b1[2304 + uD];
    }
  }
  float cst0A = 0.f, cst0B = 0.f, cst1C = 0.f, cst1D = 0.f;
  const int sl = (lane & 15) < 4 ? (lane & 15) : 3;   // h-frag row (pad rows clamped)
  const int abase = sl * 400 + (lane >> 4) * 4;
  const int c = tid, hrow = c >> 6, hcb = (c & 63) * 6;  // 12 dwords -> 6 packed
  const u16* wxC = wxlds + ((size_t)(tC * 24) * 64 + lane) * 8;
  const u16* wxD = wxlds + ((size_t)(tD * 24) * 64 + lane) * 8;
  int guard = 0;

  __syncthreads();  // wxlds staged

  for (int t = 0; t <= 512; ++t) {
    // ---- poll h0_{t-1} (tag t, slot t&1): published EARLY last macro-step ----
    i32x4 va, vb, vc2;
    {
      const int e = t;
      int* s0 = hbuf0 + (size_t)(g * 2 + (t & 1)) * 3072;
      const int* q0 = s0 + 12 * c;
      const int* q1 = q0 + 4;
      const int* q2 = q0 + 8;
      for (;;) {
        asm volatile("global_load_dwordx4 %0, %3, off sc0 sc1\n\t"
                     "global_load_dwordx4 %1, %4, off sc0 sc1\n\t"
                     "global_load_dwordx4 %2, %5, off sc0 sc1\n\t"
                     "s_waitcnt vmcnt(0)"
                     : "=&v"(va), "=&v"(vb), "=&v"(vc2)
                     : "v"(q0), "v"(q1), "v"(q2) : "memory");
        bool ok = true;
#pragma unroll
        for (int j = 0; j < 4; ++j)
          ok = ok && ((va[j] & 0xffff) == e) && ((vb[j] & 0xffff) == e) &&
               ((vc2[j] & 0xffff) == e);
        if (ok || ++guard > (1 << 22)) break;
      }
    }
    // ---- poll h1_{t-2} (tag t-1, slot (t-1)&1): the late one, own spin loop ----
    i32x4 wa, wb, wc2;
    if (t >= 1) {
      const int e = t - 1;
      int* s1 = hbuf1 + (size_t)(g * 2 + ((t - 1) & 1)) * 3072;
      const int* q0 = s1 + 12 * c;
      const int* q1 = q0 + 4;
      const int* q2 = q0 + 8;
      for (;;) {
        asm volatile("global_load_dwordx4 %0, %3, off sc0 sc1\n\t"
                     "global_load_dwordx4 %1, %4, off sc0 sc1\n\t"
                     "global_load_dwordx4 %2, %5, off sc0 sc1\n\t"
                     "s_waitcnt vmcnt(0)"
                     : "=&v"(wa), "=&v"(wb), "=&v"(wc2)
                     : "v"(q0), "v"(q1), "v"(q2) : "memory");
        bool ok = true;
#pragma unroll
        for (int j = 0; j < 4; ++j)
          ok = ok && ((wa[j] & 0xffff) == e) && ((wb[j] & 0xffff) == e) &&
               ((wc2[j] & 0xffff) == e);
        if (ok || ++guard > (1 << 22)) break;
      }
    }
    __syncthreads();  // B_A: step t-1 MFMAs done reading hlds

    {
      int2 o;
      o.x = pk2(va[0], va[1]); o.y = pk2(va[2], va[3]);
      *(int2*)&h0lds[hrow * 400 + hcb] = o;
      o.x = pk2(vb[0], vb[1]); o.y = pk2(vb[2], vb[3]);
      *(int2*)&h0lds[hrow * 400 + hcb + 2] = o;
      o.x = pk2(vc2[0], vc2[1]); o.y = pk2(vc2[2], vc2[3]);
      *(int2*)&h0lds[hrow * 400 + hcb + 4] = o;
      if (t >= 1) {
        o.x = pk2(wa[0], wa[1]); o.y = pk2(wa[2], wa[3]);
        *(int2*)&h1lds[hrow * 400 + hcb] = o;
        o.x = pk2(wb[0], wb[1]); o.y = pk2(wb[2], wb[3]);
        *(int2*)&h1lds[hrow * 400 + hcb + 2] = o;
        o.x = pk2(wc2[0], wc2[1]); o.y = pk2(wc2[2], wc2[3]);
        *(int2*)&h1lds[hrow * 400 + hcb + 4] = o;
      }
    }
    __syncthreads();  // B3: staged

    // ================= layer 0 (t < 512): critical chain =================
    if (t < 512) {
      f32x4 aE = {0, 0, 0, 0}, aO = {0, 0, 0, 0}, bE = {0, 0, 0, 0}, bO = {0, 0, 0, 0};
#pragma unroll
      for (int kk = 0; kk < 12; ++kk) {
        bf16x8 he = *(const bf16x8*)(h0lds + abase + (2 * kk) * 16);
        bf16x8 ho = *(const bf16x8*)(h0lds + abase + (2 * kk + 1) * 16);
        aE = __builtin_amdgcn_mfma_f32_16x16x32_bf16(fA[2 * kk], he, aE, 0, 0, 0);
        aO = __builtin_amdgcn_mfma_f32_16x16x32_bf16(fA[2 * kk + 1], ho, aO, 0, 0, 0);
        if (pA) {
          bE = __builtin_amdgcn_mfma_f32_16x16x32_bf16(fB[2 * kk], he, bE, 0, 0, 0);
          bO = __builtin_amdgcn_mfma_f32_16x16x32_bf16(fB[2 * kk + 1], ho, bO, 0, 0, 0);
        }
      }
      aE += aO; bE += bO;
      if (cellt) {
        int* dstb = hbuf0 + (size_t)(g * 2 + ((t + 1) & 1)) * 3072 + r * 768;
        {
          float p0g = xA0 + aE[0] + bA0, p1g = xA1 + aE[1] + bA1;
          float p2g = xA2 + aE[2] + bA2, p3g = xA3 + aE[3] + bA3;
          float ig = sigm(p0g), fg = sigm(p1g), gg = tanh_f(p2g), og = sigm(p3g);
          cst0A = fg * cst0A + ig * gg;
          float h = og * tanh_f(cst0A);
          __hip_atomic_store(dstb + uA,
              (int)(((unsigned)f2bf(h) << 16) | (unsigned)(t + 1)), __ATOMIC_RELAXED, AGENT);
        }
        if (pA) {
          float p0g = xB0 + bE[0] + bB0, p1g = xB1 + bE[1] + bB1;
          float p2g = xB2 + bE[2] + bB2, p3g = xB3 + bE[3] + bB3;
          float ig = sigm(p0g), fg = sigm(p1g), gg = tanh_f(p2g), og = sigm(p3g);
          cst0B = fg * cst0B + ig * gg;
          float h = og * tanh_f(cst0B);
          __hip_atomic_store(dstb + uB,
              (int)(((unsigned)f2bf(h) << 16) | (unsigned)(t + 1)), __ATOMIC_RELAXED, AGENT);
        }
        if (t + 1 < 512) {  // next-step xg prefetch (off critical path)
          const u16* xr = xg + ((size_t)seq * 512 + t + 1) * 3072;
          xA0 = bf2f(xr[uA]); xA1 = bf2f(xr[768 + uA]);
          xA2 = bf2f(xr[1536 + uA]); xA3 = bf2f(xr[2304 + uA]);
          if (pA) {
            xB0 = bf2f(xr[uB]); xB1 = bf2f(xr[768 + uB]);
            xB2 = bf2f(xr[1536 + uB]); xB3 = bf2f(xr[2304 + uB]);
          }
        }
      }
    }
    __builtin_amdgcn_sched_barrier(0);  // keep L0 publish ahead of L1 work

    // ================= layer 1 (t >= 1): in the handshake shadow =================
    if (t >= 1) {
      f32x4 cE = {0, 0, 0, 0}, cO = {0, 0, 0, 0}, dE = {0, 0, 0, 0}, dO = {0, 0, 0, 0};
#pragma unroll
      for (int kk = 0; kk < 12; ++kk) {
        bf16x8 h0e = *(const bf16x8*)(h0lds + abase + (2 * kk) * 16);
        bf16x8 h0o = *(const bf16x8*)(h0lds + abase + (2 * kk + 1) * 16);
        bf16x8 h1e = *(const bf16x8*)(h1lds + abase + (2 * kk) * 16);
        bf16x8 h1o = *(const bf16x8*)(h1lds + abase + (2 * kk + 1) * 16);
        bf16x8 xce = *(const bf16x8*)(wxC + (size_t)(2 * kk) * 512);
        bf16x8 xco = *(const bf16x8*)(wxC + (size_t)(2 * kk + 1) * 512);
        cE = __builtin_amdgcn_mfma_f32_16x16x32_bf16(xce, h0e, cE, 0, 0, 0);
        cO = __builtin_amdgcn_mfma_f32_16x16x32_bf16(xco, h0o, cO, 0, 0, 0);
        if (pA) {
          cE = __builtin_amdgcn_mfma_f32_16x16x32_bf16(fC[2 * kk], h1e, cE, 0, 0, 0);
          cO = __builtin_amdgcn_mfma_f32_16x16x32_bf16(fC[2 * kk + 1], h1o, cO, 0, 0, 0);
        } else {
          cE = __builtin_amdgcn_mfma_f32_16x16x32_bf16(fB[2 * kk], h1e, cE, 0, 0, 0);
          cO = __builtin_amdgcn_mfma_f32_16x16x32_bf16(fB[2 * kk + 1], h1o, cO, 0, 0, 0);
          bf16x8 xde = *(const bf16x8*)(wxD + (size_t)(2 * kk) * 512);
          bf16x8 xdo = *(const bf16x8*)(wxD + (size_t)(2 * kk + 1) * 512);
          dE = __builtin_amdgcn_mfma_f32_16x16x32_bf16(xde, h0e, dE, 0, 0, 0);
          dO = __builtin_amdgcn_mfma_f32_16x16x32_bf16(xdo, h0o, dO, 0, 0, 0);
          dE = __builtin_amdgcn_mfma_f32_16x16x32_bf16(fC[2 * kk], h1e, dE, 0, 0, 0);
          dO = __builtin_amdgcn_mfma_f32_16x16x32_bf16(fC[2 * kk + 1], h1o, dO, 0, 0, 0);
        }
      }
      cE += cO; dE += dO;
      if (cellt) {
        int* dstb = hbuf1 + (size_t)(g * 2 + (t & 1)) * 3072 + r * 768;
        size_t ob = ((size_t)seq * 512 + (t - 1)) * 768;
        {
          float p0g = cE[0] + bC0, p1g = cE[1] + bC1;
          float p2g = cE[2] + bC2, p3g = cE[3] + bC3;
          float ig = sigm(p0g), fg = sigm(p1g), gg = tanh_f(p2g), og = sigm(p3g);
          cst1C = fg * cst1C + ig * gg;
          float h = og * tanh_f(cst1C);
          __hip_atomic_store(dstb + uC,
              (int)(((unsigned)f2bf(h) << 16) | (unsigned)t), __ATOMIC_RELAXED, AGENT);
          out[ob + uC] = h;
        }
        if (!pA) {
          float p0g = dE[0] + bD0, p1g = dE[1] + bD1;
          float p2g = dE[2] + bD2, p3g = dE[3] + bD3;
          float ig = sigm(p0g), fg = sigm(p1g), gg = tanh_f(p2g), og = sigm(p3g);
          cst1D = fg * cst1D + ig * gg;
          float h = og * tanh_f(cst1D);
          __hip_atomic_store(dstb + uD,
              (int)(((unsigned)f2bf(h) << 16) | (unsigned)t), __ATOMIC_RELAXED, AGENT);
          out[ob + uD] = h;
        }
      }
    }
  }
}

// ---------- LayerNorm (in-place safe) ----------
__global__ __launch_bounds__(256) void k_ln(const float* __restrict__ in, const float* __restrict__ sc,
                                            const float* __restrict__ bi, float* __restrict__ out) {
  const int row = blockIdx.x, tid = threadIdx.x;
  const float* x = in + (size_t)row * 768;
  float v0 = x[tid], v1 = x[tid + 256], v2 = x[tid + 512];
  float s = v0 + v1 + v2;
  float s2 = v0 * v0 + v1 * v1 + v2 * v2;
#pragma unroll
  for (int off = 32; off >= 1; off >>= 1) {
    s += __shfl_xor(s, off);
    s2 += __shfl_xor(s2, off);
  }
  __shared__ float red[8];
  const int wv = tid >> 6;
  if ((tid & 63) == 0) { red[wv] = s; red[4 + wv] = s2; }
  __syncthreads();
  s = red[0] + red[1] + red[2] + red[3];
  s2 = red[4] + red[5] + red[6] + red[7];
  float mean = s * (1.f / 768.f);
  float var = s2 * (1.f / 768.f) - mean * mean;
  float rs = rsqrtf(var + 1e-6f);
  float* o = out + (size_t)row * 768;
  o[tid] = (v0 - mean) * rs * sc[tid] + bi[tid];
  o[tid + 256] = (v1 - mean) * rs * sc[tid + 256] + bi[tid + 256];
  o[tid + 512] = (v2 - mean) * rs * sc[tid + 512] + bi[tid + 512];
}

extern "C" void kernel_launch(void* const* d_in, const int* in_sizes, int n_in,
                              void* d_out, int out_size, void* d_ws, size_t ws_size,
                              hipStream_t stream) {
  const float* x   = (const float*)d_in[0];
  const float* Wx0 = (const float*)d_in[1];
  const float* Wh0 = (const float*)d_in[2];
  const float* b0  = (const float*)d_in[3];
  const float* Wx1 = (const float*)d_in[4];
  const float* Wh1 = (const float*)d_in[5];
  const float* b1  = (const float*)d_in[6];
  const float* lns = (const float*)d_in[7];
  const float* lnb = (const float*)d_in[8];
  float* out = (float*)d_out;

  char* p = (char*)d_ws;
  auto alloc = [&](size_t bytes) {
    char* r = p;
    p += (bytes + 255) & ~(size_t)255;
    return r;
  };
  u16* xg    = (u16*)alloc(16384ull * 3072 * 2);
  u16* xbf   = (u16*)alloc(16384ull * 768 * 2);
  u16* Wxp0  = (u16*)alloc(2359296ull * 2);
  u16* Whp0s = (u16*)alloc(2359296ull * 2);
  u16* Whp1s = (u16*)alloc(2359296ull * 2);
  u16* Wxp1s = (u16*)alloc(2359296ull * 2);
  char* sync0 = alloc(196608ull * 2);   // hbuf0, hbuf1 (tagged dwords)
  int* hbuf0 = (int*)sync0;
  int* hbuf1 = (int*)(sync0 + 196608);

  if ((size_t)(p - (char*)d_ws) > ws_size) {
    fprintf(stderr, "kernel_launch: ws too small: need %zu have %zu\n",
            (size_t)(p - (char*)d_ws), ws_size);
    return;
  }

  hipMemsetAsync(sync0, 0, 196608ull * 2, stream);
  k_cvt<<<12288, 256, 0, stream>>>(x, xbf, 3145728);
  k_pack_wx<<<9216, 256, 0, stream>>>(Wx0, Wxp0);
  k_pack_wh<<<9216, 256, 0, stream>>>(Wh0, Whp0s);
  k_pack_wh<<<9216, 256, 0, stream>>>(Wh1, Whp1s);
  k_pack_wh<<<9216, 256, 0, stream>>>(Wx1, Wxp1s);

  k_gemm<<<3072, 256, 0, stream>>>(xbf, Wxp0, xg);
  k_rec2<<<256, 256, 0, stream>>>(xg, Whp0s, Whp1s, Wxp1s, b0, b1, hbuf0, hbuf1, (float*)d_out);
  k_ln<<<16384, 256, 0, stream>>>((const float*)d_out, lns, lnb, out);
}

// Round 17
// 2147.622 us; speedup vs baseline: 2.0635x; 1.8785x over previous
//
#include <hip/hip_runtime.h>
#include <stdint.h>
#include <cstdio>

typedef unsigned short u16;
typedef __attribute__((ext_vector_type(8))) __bf16 bf16x8;
typedef __attribute__((ext_vector_type(4))) float f32x4;
typedef __attribute__((ext_vector_type(4))) int i32x4;

#define AGENT __HIP_MEMORY_SCOPE_AGENT

__device__ __forceinline__ float bf2f(u16 u) {
  unsigned int x = ((unsigned int)u) << 16;
  return __builtin_bit_cast(float, x);
}
__device__ __forceinline__ u16 f2bf(float f) {
  unsigned int x = __builtin_bit_cast(unsigned int, f);
  unsigned int r = (x + 0x7fffu + ((x >> 16) & 1u)) >> 16;
  return (u16)r;
}
__device__ __forceinline__ float sigm(float x) { return 1.f / (1.f + __expf(-x)); }
__device__ __forceinline__ float tanh_f(float x) { return 1.f - 2.f / (__expf(2.f * x) + 1.f); }

// ---------- fp32 -> bf16 convert (x) ----------
__global__ __launch_bounds__(256) void k_cvt(const float* __restrict__ in, u16* __restrict__ out, int n4) {
  int i = blockIdx.x * 256 + threadIdx.x;
  if (i >= n4) return;
  float4 f = ((const float4*)in)[i];
  ushort4 o;
  o.x = f2bf(f.x); o.y = f2bf(f.y); o.z = f2bf(f.z); o.w = f2bf(f.w);
  ((ushort4*)out)[i] = o;
}

// ---------- pack Wx [768][3072] -> B-fragment order [nt=192][kt=24][lane=64][j=8] ----------
__global__ __launch_bounds__(256) void k_pack_wx(const float* __restrict__ Wx, u16* __restrict__ Bp) {
  int idx = blockIdx.x * 256 + threadIdx.x;
  if (idx >= 2359296) return;
  int j = idx & 7;
  int l = (idx >> 3) & 63;
  int t = idx >> 9;          // nt*24 + kt
  int kt = t % 24, nt = t / 24;
  int k = kt * 32 + (l >> 4) * 8 + j;
  int n = nt * 16 + (l & 15);
  Bp[idx] = f2bf(Wx[(size_t)k * 3072 + n]);
}

// ---------- pack Wh -> per-member slices [w=32][nt=6][kt=24][lane=64][j=8] ----------
// col order within 16-col tile: cc = 4*vi + q (vi = unit-in-wave 0..3, q = gate 0..3)
// Serves as the A-operand (rows = cc) of the swapped MFMA.
__global__ __launch_bounds__(256) void k_pack_wh(const float* __restrict__ Wh, u16* __restrict__ Wp) {
  int idx = blockIdx.x * 256 + threadIdx.x;
  if (idx >= 2359296) return;
  int j = idx & 7;
  int l = (idx >> 3) & 63;
  int t = idx >> 9;          // w*144 + nt*24 + kt
  int kt = t % 24;
  int tmp = t / 24;          // w*6 + nt
  int nt = tmp % 6, w = tmp / 6;
  int k = kt * 32 + (l >> 4) * 8 + j;
  int cc = l & 15;
  int vi = cc >> 2, q = cc & 3;
  int gcol = q * 768 + w * 24 + nt * 4 + vi;
  Wp[idx] = f2bf(Wh[(size_t)k * 3072 + gcol]);
}

// ---------- GEMM: C[16384][3072] bf16 = A[16384][768] bf16 @ Bp(packed) ----------
__global__ __launch_bounds__(256, 2) void k_gemm(const u16* __restrict__ A, const u16* __restrict__ Bp,
                                                 u16* __restrict__ C) {
  const int bid = blockIdx.x;
  const int bm = bid & 127, bn = bid >> 7;   // 128 x 24
  const int tid = threadIdx.x, lane = tid & 63, wv = tid >> 6;
  const int wm = wv >> 1, wn = wv & 1;
  const int row0 = bm * 128 + wm * 64;
  const int col0 = bn * 128 + wn * 64;
  const int rlo = lane & 15, rhi = lane >> 4;
  f32x4 acc[4][4] = {};
  const u16* Ab = A + (size_t)(row0 + rlo) * 768 + rhi * 8;
  const u16* Bb = Bp + ((size_t)(bn * 8 + wn * 4) * 24 * 64 + lane) * 8;
#pragma unroll 2
  for (int kt = 0; kt < 24; ++kt) {
    bf16x8 a[4], b[4];
#pragma unroll
    for (int i = 0; i < 4; ++i) a[i] = *(const bf16x8*)(Ab + (size_t)i * 16 * 768 + kt * 32);
#pragma unroll
    for (int j = 0; j < 4; ++j) b[j] = *(const bf16x8*)(Bb + (size_t)j * 24 * 64 * 8 + (size_t)kt * 64 * 8);
#pragma unroll
    for (int i = 0; i < 4; ++i)
#pragma unroll
      for (int j = 0; j < 4; ++j)
        acc[i][j] = __builtin_amdgcn_mfma_f32_16x16x32_bf16(a[i], b[j], acc[i][j], 0, 0, 0);
  }
#pragma unroll
  for (int i = 0; i < 4; ++i)
#pragma unroll
    for (int j = 0; j < 4; ++j)
#pragma unroll
      for (int r = 0; r < 4; ++r) {
        int row = row0 + i * 16 + rhi * 4 + r;
        int col = col0 + j * 16 + rlo;
        C[(size_t)row * 3072 + col] = f2bf(acc[i][j][r]);
      }
}

// ---------- persistent LSTM recurrence ----------
// 256 WGs x 384 threads (6 waves) — proven optimum (R12/R14). Logical groups: g = wid&7
// (4 seqs), member w = wid>>3 (24 units). Wave wv owns one 16-col tile = 4 gates x 4 units.
// Per step: merged poll+fetch of tagged h_{t-1} (full load IS the poll, 1 LLC RT) -> B_A ->
// stage hlds -> B3 -> swapped MFMA D[cc][seq] (lane 16*vi + r holds all 4 gates of cell
// (seq r, unit vi)) -> cell math from acc -> fire-and-forget tagged publish, parity dbuf.
// Weight frags loaded via inline-asm (guaranteed register/AGPR-resident).
__global__ __launch_bounds__(384) void k_rec(
    const u16* __restrict__ xg,    // [16384][3072] bf16, m = seq*512 + t
    const u16* __restrict__ Whp,   // [32][6][24][64][8] packed bf16
    const float* __restrict__ bias,
    int* hbuf,                     // [8 groups][2][3072] tagged dwords (zeroed)
    u16* __restrict__ hout_bf,     // layer 0 out (bf16) or null
    float* __restrict__ hout_f,    // layer 1 out (fp32) or null
    int layer) {
  __shared__ __align__(16) int hlds[4 * 400];   // h_{t-1}[4 seq][768] bf16, rows padded to 400 dw

  const int wid = blockIdx.x, g = wid & 7, w = wid >> 3;
  const int tid = threadIdx.x, lane = tid & 63, wv = tid >> 6;

  // ---- Wh fragments -> registers, FORCED resident (asm loads can't be rematerialized) ----
  i32x4 wE[12], wO[12];
  {
    const u16* bp = Whp + (((size_t)(w * 6 + wv) * 24) * 64 + lane) * 8;
#pragma unroll
    for (int kk = 0; kk < 12; ++kk) {
      const u16* pe = bp + (size_t)(2 * kk) * 512;
      const u16* po = bp + (size_t)(2 * kk + 1) * 512;
      asm volatile("global_load_dwordx4 %0, %2, off\n\t"
                   "global_load_dwordx4 %1, %3, off"
                   : "=&v"(wE[kk]), "=&v"(wO[kk])
                   : "v"(pe), "v"(po));
    }
    asm volatile("s_waitcnt vmcnt(0)");
  }

  // ---- cell role: lane = 16*vi + r owns cell (seq r, unit vi) ----
  const bool cellt = (lane & 15) < 4;
  const int vi = lane >> 4, r = lane & 3;
  const int unit = w * 24 + wv * 4 + vi;
  const int seq = g * 4 + r;
  float bv0 = 0, bv1 = 0, bv2 = 0, bv3 = 0, xv0 = 0, xv1 = 0, xv2 = 0, xv3 = 0;
  if (cellt) {
    bv0 = bias[unit]; bv1 = bias[768 + unit]; bv2 = bias[1536 + unit]; bv3 = bias[2304 + unit];
    const u16* xr = xg + (size_t)seq * 512 * 3072;
    xv0 = bf2f(xr[unit]); xv1 = bf2f(xr[768 + unit]);
    xv2 = bf2f(xr[1536 + unit]); xv3 = bf2f(xr[2304 + unit]);
  }
  float cst = 0.f;
  const int sl = (lane & 15) < 4 ? (lane & 15) : 3;      // h-frag row (pad rows clamped)
  const int abase = sl * 400 + (lane >> 4) * 4;          // h-frag dword base in hlds
  // poll/stage role: thread tid handles 8 tagged dwords
  const int c = tid;                                     // 0..383
  const int hrow = c / 96, hcol = (c % 96) * 4;          // packed int4 slot in hlds
  int guard = 0;

  __syncthreads();

  for (int t = 0; t < 512; ++t) {
    // ---- merged poll+fetch of h_{t-1}: full tagged load IS the poll (1 RT) ----
    const int expect = t;  // tag written by step t-1 producers (t=0: zeroed buffer)
    int* src = hbuf + (size_t)(g * 2 + (t & 1)) * 3072;
    const int* p0 = src + 8 * c;
    const int* p1 = src + 8 * c + 4;
    i32x4 v0, v1;
    for (;;) {
      asm volatile("global_load_dwordx4 %0, %2, off sc0 sc1\n\t"
                   "global_load_dwordx4 %1, %3, off sc0 sc1\n\t"
                   "s_waitcnt vmcnt(0)"
                   : "=&v"(v0), "=&v"(v1)
                   : "v"(p0), "v"(p1)
                   : "memory");
      bool ok = true;
#pragma unroll
      for (int j = 0; j < 4; ++j)
        ok = ok && ((v0[j] & 0xffff) == expect) && ((v1[j] & 0xffff) == expect);
      if (ok || ++guard > (1 << 22)) break;
    }
    __syncthreads();  // B_A: all waves done reading hlds (MFMA of t-1)

    // stage packed bf16 pairs into hlds
    {
      int4 pk;
      pk.x = (int)(((unsigned)v0[0] >> 16) | ((unsigned)v0[1] & 0xffff0000u));
      pk.y = (int)(((unsigned)v0[2] >> 16) | ((unsigned)v0[3] & 0xffff0000u));
      pk.z = (int)(((unsigned)v1[0] >> 16) | ((unsigned)v1[1] & 0xffff0000u));
      pk.w = (int)(((unsigned)v1[2] >> 16) | ((unsigned)v1[3] & 0xffff0000u));
      *(int4*)&hlds[hrow * 400 + hcol] = pk;
    }
    __syncthreads();  // B3: hlds ready

    // ---- MFMA (swapped): D[cc][seq] = W(A) x h(B), kt-parity 2 chains ----
    f32x4 a0 = {0, 0, 0, 0}, a1 = {0, 0, 0, 0};
#pragma unroll
    for (int kk = 0; kk < 12; ++kk) {
      bf16x8 afe = *(const bf16x8*)(hlds + abase + (2 * kk) * 16);
      bf16x8 afo = *(const bf16x8*)(hlds + abase + (2 * kk + 1) * 16);
      a0 = __builtin_amdgcn_mfma_f32_16x16x32_bf16(__builtin_bit_cast(bf16x8, wE[kk]), afe, a0, 0, 0, 0);
      a1 = __builtin_amdgcn_mfma_f32_16x16x32_bf16(__builtin_bit_cast(bf16x8, wO[kk]), afo, a1, 0, 0, 0);
    }
    a0 += a1;
    // D layout: row = cc = (lane>>4)*4 + reg, col = seq = lane&15
    // -> lane 16*vi + r holds gates q=0..3 (i,f,g,o) of cell (seq r, unit vi) in a0[0..3]

    if (cellt) {
      float p0g = xv0 + a0[0] + bv0;
      float p1g = xv1 + a0[1] + bv1;
      float p2g = xv2 + a0[2] + bv2;
      float p3g = xv3 + a0[3] + bv3;
      float ig = sigm(p0g), fg = sigm(p1g), gg = tanh_f(p2g), og = sigm(p3g);
      cst = fg * cst + ig * gg;
      float h = og * tanh_f(cst);
      // publish tagged h (fire-and-forget; dword atomicity makes it self-validating)
      int* dst = hbuf + (size_t)(g * 2 + ((t + 1) & 1)) * 3072 + r * 768 + unit;
      int val = (int)(((unsigned)f2bf(h) << 16) | (unsigned)(t + 1));
      __hip_atomic_store(dst, val, __ATOMIC_RELAXED, AGENT);
      // off the critical path: output store + next-step xg prefetch
      size_t o = ((size_t)seq * 512 + t) * 768 + unit;
      if (layer == 0) hout_bf[o] = f2bf(h); else hout_f[o] = h;
      if (t + 1 < 512) {
        const u16* xr = xg + ((size_t)seq * 512 + t + 1) * 3072;
        xv0 = bf2f(xr[unit]); xv1 = bf2f(xr[768 + unit]);
        xv2 = bf2f(xr[1536 + unit]); xv3 = bf2f(xr[2304 + unit]);
      }
    }
  }
}

// ---------- LayerNorm (in-place safe) ----------
__global__ __launch_bounds__(256) void k_ln(const float* __restrict__ in, const float* __restrict__ sc,
                                            const float* __restrict__ bi, float* __restrict__ out) {
  const int row = blockIdx.x, tid = threadIdx.x;
  const float* x = in + (size_t)row * 768;
  float v0 = x[tid], v1 = x[tid + 256], v2 = x[tid + 512];
  float s = v0 + v1 + v2;
  float s2 = v0 * v0 + v1 * v1 + v2 * v2;
#pragma unroll
  for (int off = 32; off >= 1; off >>= 1) {
    s += __shfl_xor(s, off);
    s2 += __shfl_xor(s2, off);
  }
  __shared__ float red[8];
  const int wv = tid >> 6;
  if ((tid & 63) == 0) { red[wv] = s; red[4 + wv] = s2; }
  __syncthreads();
  s = red[0] + red[1] + red[2] + red[3];
  s2 = red[4] + red[5] + red[6] + red[7];
  float mean = s * (1.f / 768.f);
  float var = s2 * (1.f / 768.f) - mean * mean;
  float rs = rsqrtf(var + 1e-6f);
  float* o = out + (size_t)row * 768;
  o[tid] = (v0 - mean) * rs * sc[tid] + bi[tid];
  o[tid + 256] = (v1 - mean) * rs * sc[tid + 256] + bi[tid + 256];
  o[tid + 512] = (v2 - mean) * rs * sc[tid + 512] + bi[tid + 512];
}

extern "C" void kernel_launch(void* const* d_in, const int* in_sizes, int n_in,
                              void* d_out, int out_size, void* d_ws, size_t ws_size,
                              hipStream_t stream) {
  const float* x   = (const float*)d_in[0];
  const float* Wx0 = (const float*)d_in[1];
  const float* Wh0 = (const float*)d_in[2];
  const float* b0  = (const float*)d_in[3];
  const float* Wx1 = (const float*)d_in[4];
  const float* Wh1 = (const float*)d_in[5];
  const float* b1  = (const float*)d_in[6];
  const float* lns = (const float*)d_in[7];
  const float* lnb = (const float*)d_in[8];
  float* out = (float*)d_out;

  char* p = (char*)d_ws;
  auto alloc = [&](size_t bytes) {
    char* r = p;
    p += (bytes + 255) & ~(size_t)255;
    return r;
  };
  u16* xg    = (u16*)alloc(16384ull * 3072 * 2);
  u16* xbf   = (u16*)alloc(16384ull * 768 * 2);
  u16* h0bf  = (u16*)alloc(16384ull * 768 * 2);
  u16* Wxp0  = (u16*)alloc(2359296ull * 2);
  u16* Wxp1  = (u16*)alloc(2359296ull * 2);
  u16* Whp0  = (u16*)alloc(2359296ull * 2);
  u16* Whp1  = (u16*)alloc(2359296ull * 2);
  char* sync0 = alloc(196608ull * 2);   // hbuf0, hbuf1 (tagged dwords)
  int* hbuf0 = (int*)sync0;
  int* hbuf1 = (int*)(sync0 + 196608);

  if ((size_t)(p - (char*)d_ws) > ws_size) {
    fprintf(stderr, "kernel_launch: ws too small: need %zu have %zu\n",
            (size_t)(p - (char*)d_ws), ws_size);
    return;
  }

  hipMemsetAsync(sync0, 0, 196608ull * 2, stream);
  k_cvt<<<12288, 256, 0, stream>>>(x, xbf, 3145728);
  k_pack_wx<<<9216, 256, 0, stream>>>(Wx0, Wxp0);
  k_pack_wx<<<9216, 256, 0, stream>>>(Wx1, Wxp1);
  k_pack_wh<<<9216, 256, 0, stream>>>(Wh0, Whp0);
  k_pack_wh<<<9216, 256, 0, stream>>>(Wh1, Whp1);

  k_gemm<<<3072, 256, 0, stream>>>(xbf, Wxp0, xg);
  k_rec<<<256, 384, 0, stream>>>(xg, Whp0, b0, hbuf0, h0bf, nullptr, 0);
  k_gemm<<<3072, 256, 0, stream>>>(h0bf, Wxp1, xg);
  k_rec<<<256, 384, 0, stream>>>(xg, Whp1, b1, hbuf1, nullptr, (float*)d_out, 1);
  k_ln<<<16384, 256, 0, stream>>>((const float*)d_out, lns, lnb, out);
}